// Round 6
// baseline (3805.869 us; speedup 1.0000x reference)
//
#include <hip/hip_runtime.h>

#define TT 512
#define II 128
#define HH 1024
#define BB 64

typedef __attribute__((ext_vector_type(8))) short bf16x8;
typedef __attribute__((ext_vector_type(4))) float f32x4;

__device__ __forceinline__ unsigned short f2bf(float f) {
  unsigned u = __builtin_bit_cast(unsigned, f);
  u += 0x7fffu + ((u >> 16) & 1u);   // round-to-nearest-even
  return (unsigned short)(u >> 16);
}

__device__ __forceinline__ bf16x8 load8f_bf(const float* p) {
  const f32x4* q = (const f32x4*)p;
  f32x4 a = q[0];
  f32x4 b = q[1];
  bf16x8 r;
  r[0] = (short)f2bf(a[0]); r[1] = (short)f2bf(a[1]);
  r[2] = (short)f2bf(a[2]); r[3] = (short)f2bf(a[3]);
  r[4] = (short)f2bf(b[0]); r[5] = (short)f2bf(b[1]);
  r[6] = (short)f2bf(b[2]); r[7] = (short)f2bf(b[3]);
  return r;
}

__device__ __forceinline__ float sigm(float v) { return 1.f / (1.f + __expf(-v)); }
__device__ __forceinline__ float tanh_f(float v) { return 2.f / (1.f + __expf(-2.f * v)) - 1.f; }

// R1/R5-verified coherence recipe (fastest of rounds 0-5):
//   producers: sc0sc1 write-through stores (land at LLC, acked by vmcnt)
//   consumers: PLAIN cached loads + agent-acquire (buffer_inv, invalidate-
//              only; dirty lines incl. scratch spills survive) once per step.
// R3: agent-atomic h loads = +0.9us/step (no L2 sharing). R4: no-spill
// geometry = +3.7us/step. Do not revisit either.
__device__ __forceinline__ void st_short_sc(unsigned short* p, unsigned short v) {
  unsigned vv = v;
  asm volatile("global_store_short %0, %1, off sc0 sc1" :: "v"(p), "v"(vv) : "memory");
}
__device__ __forceinline__ void st_dword_sc(float* p, float v) {
  asm volatile("global_store_dword %0, %1, off sc0 sc1" :: "v"(p), "v"(v) : "memory");
}

// Monotonic 16-way-split group barrier (R5-verified, -0.55us/step vs single
// counter), round-6 hardened against TCC queue congestion:
//  - counters 256 B apart (one TCC channel each; R5's 64 B stride packed all
//    16 onto ~4 channels, so arrives/polls queued behind each other),
//  - poll backoff (sleep 1,2,2,2,8,8,...): cuts the 1024-lane coherent-load
//    storm during the wait window ~3x; detect-latency cap ~213ns,
//  - wave 1 arrives+polls (wave 0 is the busiest compute wave).
// Counters monotone (+4/step each); target for barrier #b is 4*b.
__device__ __forceinline__ void group_barrier(int* bar, int g, int rank, int tgt) {
  __syncthreads();
  const int t0 = (int)threadIdx.x - 64;   // wave 1
  if (t0 >= 0 && t0 < 64) {
    if (t0 == (rank & 15))
      __hip_atomic_fetch_add(bar + (g * 16 + t0) * 64, 1,
          __ATOMIC_RELAXED, __HIP_MEMORY_SCOPE_AGENT);
    int spins = 0;
    bool ok;
    do {
      int v = tgt;
      if (t0 < 16)
        v = __hip_atomic_load(bar + (g * 16 + t0) * 64,
            __ATOMIC_RELAXED, __HIP_MEMORY_SCOPE_AGENT);
      ok = __all(v >= tgt);
      if (!ok) {
        if (spins == 0) __builtin_amdgcn_s_sleep(1);
        else if (spins < 4) __builtin_amdgcn_s_sleep(2);
        else __builtin_amdgcn_s_sleep(8);
        ++spins;
      }
    } while (!ok);
    __builtin_amdgcn_fence(__ATOMIC_ACQUIRE, "agent");  // inv only (no wbl2)
  }
  __syncthreads();
}

// 256 WGs x 512 threads (8 waves), 1 WG/CU. 4 groups x 64 WGs; group g owns
// batches [16g,16g+16). WG owns 16 hidden units per layer.
// Waves 0-3: layer0 (K=1152, 4-way split, 9 kt each, weights in VGPRs).
// Waves 4-7: layer1 (K=2048, 4-way split, 16 kt: 9 in VGPRs + 7 in LDS).
// GEOMETRY SETTLED (R0-R4): 4x64 beats 2x128; the ~150KB/WG weight spill is
// L2-dirty-resident (survives buffer_inv) and cheap. Leave it alone.
//
// ROUND 6: kill the two per-step TCC storms.
//  (a) FC output: was 64 WGs x 16 lanes atomicAdd on the SAME 16 global
//      addresses every step = 1024 serialized same-line LLC RMWs queueing
//      ahead of barrier counters / h stores. Now: quarter-wave shuffle
//      reduce -> one sc store per (WG, batch) into a private slot array;
//      post-loop parallel pass reduces 64 slots -> out (once, ~5us).
//  (b) poll storm + channel packing: see group_barrier.
__global__ __attribute__((amdgpu_waves_per_eu(2, 2))) __launch_bounds__(512)
void lstm_persistent(
    const float* __restrict__ x, const float* __restrict__ h0,
    const float* __restrict__ c0,
    const float* __restrict__ Wih0, const float* __restrict__ Whh0,
    const float* __restrict__ bih0, const float* __restrict__ bhh0,
    const float* __restrict__ Wih1, const float* __restrict__ Whh1,
    const float* __restrict__ bih1, const float* __restrict__ bhh1,
    const float* __restrict__ Wfc, const float* __restrict__ bfc,
    float* __restrict__ out, unsigned short* __restrict__ hbuf,
    float* __restrict__ part, int slotmode, int* __restrict__ bar)
{
  const int tid  = threadIdx.x;
  const int lane = tid & 63;
  const int wv   = tid >> 6;         // 0..7
  const int L    = wv >> 2;          // 0: layer0 waves, 1: layer1 waves
  const int kwv  = wv & 3;           // K-split index within layer
  const int bid  = blockIdx.x;
  const int g    = bid >> 6;
  const int rank = bid & 63;
  const int gbase = g * 16;
  const int ubase = rank * 16;

  unsigned short* h1s = hbuf;                  // [2][64][1024] bf16 double-buffered (layer0 h)
  unsigned short* h2s = hbuf + 2 * BB * HH;    // layer1 h

  __shared__ float lds_part[2][4][64][17];     // [layer][kwv][gate-row][batch pad17]
  __shared__ float lds_bias[128];
  __shared__ float lds_out[16];                // fallback mode only
  extern __shared__ __align__(16) unsigned short lds_w[];  // 4*7*4*64 frags * 16B = 114688B

  const int n  = lane & 15;
  const int ko = (lane >> 4) * 8;

  // ---- pack weights: registers (both layers) + LDS (layer1 kt 9..15) ----
  bf16x8 w[4][9];
  if (L == 0) {
#pragma unroll
    for (int nt = 0; nt < 4; ++nt) {
      int r = nt * 16 + n;                       // local row: unit=r>>2, gate=r&3
      int R = (r & 3) * HH + ubase + (r >> 2);   // gate*H + unit (i,f,g,o)
#pragma unroll
      for (int kt = 0; kt < 9; ++kt) {
        int c = kwv * 288 + kt * 32 + ko;        // col in [0,1152)
        const float* src = (c < II) ? (Wih0 + (size_t)R * II + c)
                                    : (Whh0 + (size_t)R * HH + (c - II));
        w[nt][kt] = load8f_bf(src);
      }
    }
  } else {
#pragma unroll
    for (int nt = 0; nt < 4; ++nt) {
      int r = nt * 16 + n;
      int R = (r & 3) * HH + ubase + (r >> 2);
#pragma unroll
      for (int kt = 0; kt < 16; ++kt) {
        int c = kwv * 512 + kt * 32 + ko;        // col in [0,2048)
        const float* src = (c < HH) ? (Wih1 + (size_t)R * HH + c)
                                    : (Whh1 + (size_t)R * HH + (c - HH));
        bf16x8 f = load8f_bf(src);
        if (kt < 9) {
          w[nt][kt] = f;
        } else {
          int fi = ((kwv * 7 + (kt - 9)) * 4 + nt) * 64 + lane;
          ((bf16x8*)lds_w)[fi] = f;
        }
      }
    }
  }

  // combined biases -> LDS
  if (tid < 128) {
    int Lr = tid >> 6, r = tid & 63;
    int R = (r & 3) * HH + ubase + (r >> 2);
    lds_bias[tid] = (Lr == 0) ? (bih0[R] + bhh0[R]) : (bih1[R] + bhh1[R]);
  }

  // epilogue mapping: 512 threads = 2 layers x 16 units x 16 batches
  const int eL = tid >> 8;
  const int eu = tid & 15;
  const int em = (tid >> 4) & 15;
  const int b_e = gbase + em;
  const int u_e = ubase + eu;
  float c_st = c0[eL * BB * HH + b_e * HH + u_e];
  const float wfc_r = Wfc[u_e];

  // init h double-buffers: slot 1 <- h0 (write-through: read cross-XCD at p=0/1)
  if (rank < 16) {
    int b = gbase + rank;
    for (int u = tid; u < HH; u += 512) {
      st_short_sc(&h1s[BB * HH + b * HH + u], f2bf(h0[0 * BB * HH + b * HH + u]));
      st_short_sc(&h2s[BB * HH + b * HH + u], f2bf(h0[1 * BB * HH + b * HH + u]));
    }
  }
  // fallback only: init out with b_fc (atomics accumulate onto it at LLC)
  if (!slotmode && rank == 0) {
    float bf = bfc[0];
    for (int i = tid; i < 16 * TT; i += 512)
      st_dword_sc(&out[(gbase + (i >> 9)) * TT + (i & 511)], bf);
  }
  asm volatile("s_waitcnt vmcnt(0)" ::: "memory");  // drain asm sc stores

  group_barrier(bar, g, rank, 4 * 1);

  const int bA = gbase + n;   // A-fragment batch (m = lane&15)

  for (int p = 0; p <= TT; ++p) {
    const bool l0act = (p < TT);
    const bool l1act = (p >= 1);
    const unsigned short* h1r = h1s + ((p - 1) & 1) * (BB * HH);  // h1[p-1]
    const unsigned short* h2r = h2s + (p & 1) * (BB * HH);        // h2[p-2]

    f32x4 acc[4];
#pragma unroll
    for (int nt = 0; nt < 4; ++nt) acc[nt] = (f32x4){0.f, 0.f, 0.f, 0.f};

    if (L == 0) {
      if (l0act) {
        if (kwv == 0) {
#pragma unroll
          for (int kt = 0; kt < 4; ++kt) {             // cols 0..127: from x (fp32)
            bf16x8 a = load8f_bf(x + ((size_t)bA * TT + p) * II + kt * 32 + ko);
#pragma unroll
            for (int nt = 0; nt < 4; ++nt)
              acc[nt] = __builtin_amdgcn_mfma_f32_16x16x32_bf16(a, w[nt][kt], acc[nt], 0, 0, 0);
          }
#pragma unroll
          for (int kt = 4; kt < 9; ++kt) {             // cols 128..287: h1[p-1]
            bf16x8 a = *(const bf16x8*)(h1r + (size_t)bA * HH + (kt * 32 + ko - II));
#pragma unroll
            for (int nt = 0; nt < 4; ++nt)
              acc[nt] = __builtin_amdgcn_mfma_f32_16x16x32_bf16(a, w[nt][kt], acc[nt], 0, 0, 0);
          }
        } else {
#pragma unroll
          for (int kt = 0; kt < 9; ++kt) {             // all from h1[p-1]
            int off = kwv * 288 + kt * 32 + ko - II;
            bf16x8 a = *(const bf16x8*)(h1r + (size_t)bA * HH + off);
#pragma unroll
            for (int nt = 0; nt < 4; ++nt)
              acc[nt] = __builtin_amdgcn_mfma_f32_16x16x32_bf16(a, w[nt][kt], acc[nt], 0, 0, 0);
          }
        }
      }
    } else {
      if (l1act) {
        // kwv 0,1 read h1[p-1]; kwv 2,3 read h2[p-2]
        const unsigned short* hb = (kwv < 2) ? h1r : h2r;
        const int kbase = (kwv & 1) * 512;
#pragma unroll
        for (int kt = 0; kt < 9; ++kt) {
          bf16x8 a = *(const bf16x8*)(hb + (size_t)bA * HH + kbase + kt * 32 + ko);
#pragma unroll
          for (int nt = 0; nt < 4; ++nt)
            acc[nt] = __builtin_amdgcn_mfma_f32_16x16x32_bf16(a, w[nt][kt], acc[nt], 0, 0, 0);
        }
#pragma unroll
        for (int kt = 9; kt < 16; ++kt) {
          bf16x8 a = *(const bf16x8*)(hb + (size_t)bA * HH + kbase + kt * 32 + ko);
#pragma unroll
          for (int nt = 0; nt < 4; ++nt) {
            bf16x8 wf = ((const bf16x8*)lds_w)[((kwv * 7 + (kt - 9)) * 4 + nt) * 64 + lane];
            acc[nt] = __builtin_amdgcn_mfma_f32_16x16x32_bf16(a, wf, acc[nt], 0, 0, 0);
          }
        }
      }
    }

    // stage partials to LDS (D layout: n-row = lane&15, m = (lane>>4)*4 + reg)
    {
      const bool act = (L == 0) ? l0act : l1act;
      if (act) {
        const int m0 = (lane >> 4) * 4;
#pragma unroll
        for (int nt = 0; nt < 4; ++nt) {
          int row = nt * 16 + n;
#pragma unroll
          for (int r = 0; r < 4; ++r)
            lds_part[L][kwv][row][m0 + r] = acc[nt][r];
        }
      }
    }
    __syncthreads();

    // epilogue: 1 (layer,unit,batch) per thread; c-state in register
    const bool eact = (eL == 0) ? l0act : l1act;
    if (eact) {
      float pre[4];
#pragma unroll
      for (int q = 0; q < 4; ++q) {
        float s = lds_bias[eL * 64 + eu * 4 + q];
#pragma unroll
        for (int w2 = 0; w2 < 4; ++w2)
          s += lds_part[eL][w2][eu * 4 + q][em];
        pre[q] = s;
      }
      float iv = sigm(pre[0]);
      float fv = sigm(pre[1]);
      float gv = tanh_f(pre[2]);
      float ov = sigm(pre[3]);
      c_st = fv * c_st + iv * gv;
      float hv = ov * tanh_f(c_st);
      if (eL == 0) {
        st_short_sc(&h1s[(p & 1) * (BB * HH) + b_e * HH + u_e], f2bf(hv));        // h1[p]
      } else {
        st_short_sc(&h2s[((p - 1) & 1) * (BB * HH) + b_e * HH + u_e], f2bf(hv));  // h2[p-1]
        // FC partial: reduce over the 16 units (eu) held by this quarter-wave
        // (em is constant within a quarter-wave), one value per (WG, em).
        float fcv = hv * wfc_r;
        fcv += __shfl_xor(fcv, 1);
        fcv += __shfl_xor(fcv, 2);
        fcv += __shfl_xor(fcv, 4);
        fcv += __shfl_xor(fcv, 8);
        if ((lane & 15) == 0) {
          if (slotmode) {
            // private slot: zero contention; reduced once after the loop
            st_dword_sc(&part[(((size_t)(p - 1) * 4 + g) * 16 + em) * 64 + rank], fcv);
          } else {
            lds_out[em] = fcv;   // single writer per em
          }
        }
      }
    }
    // drain asm sc stores before the arrive (invisible to waitcnt pass)
    asm volatile("s_waitcnt vmcnt(0)" ::: "memory");
    if (!slotmode) {
      __syncthreads();
      if (l1act && tid < 16)
        atomicAdd(&out[(gbase + tid) * TT + (p - 1)], lds_out[tid]);
    }

    if (p < TT) group_barrier(bar, g, rank, 4 * (p + 2));
  }

  // ---- post-loop FC reduction (slot mode): out[b][t] = bfc + sum_rank part
  if (slotmode) {
    group_barrier(bar, g, rank, 4 * (TT + 2));   // publish step-TT part stores
    const float bfc0 = bfc[0];
    const int w_id = rank * 8 + wv;              // 0..511 waves in this group
#pragma unroll 1
    for (int i = 0; i < 16; ++i) {
      int tsk = w_id * 16 + i;                   // 8192 tasks = 512 t x 16 em
      int t   = tsk >> 4;
      int emr = tsk & 15;
      float v = part[(((size_t)t * 4 + g) * 16 + emr) * 64 + lane];
#pragma unroll
      for (int d = 1; d < 64; d <<= 1) v += __shfl_xor(v, d);
      if (lane == 0) out[(gbase + emr) * TT + t] = v + bfc0;
    }
  }
}

extern "C" void kernel_launch(void* const* d_in, const int* in_sizes, int n_in,
                              void* d_out, int out_size, void* d_ws, size_t ws_size,
                              hipStream_t stream) {
  (void)in_sizes; (void)n_in; (void)out_size;
  hipMemsetAsync(d_ws, 0, 16384, stream);  // 4 groups x 16 counters x 256B
  int* bar = (int*)d_ws;
  unsigned short* hbuf = (unsigned short*)((char*)d_ws + 16384);   // 512 KB h buffers
  float* part = (float*)((char*)d_ws + (1u << 20));                // 8 MB FC slots
  int slotmode = (ws_size >= (1u << 20) + 8u * 1024u * 1024u) ? 1 : 0;
  hipLaunchKernelGGL(lstm_persistent, dim3(256), dim3(512), 114688, stream,
      (const float*)d_in[0], (const float*)d_in[1], (const float*)d_in[2],
      (const float*)d_in[3], (const float*)d_in[4], (const float*)d_in[5],
      (const float*)d_in[6], (const float*)d_in[7], (const float*)d_in[8],
      (const float*)d_in[9], (const float*)d_in[10], (const float*)d_in[11],
      (const float*)d_in[12], (float*)d_out, hbuf, part, slotmode, bar);
}